// Round 2
// baseline (3591.984 us; speedup 1.0000x reference)
//
#include <hip/hip_runtime.h>

// FFCoSTA: 15-step thermal recurrence (pbm + tiny MLP) over B=65536 elements,
// output = (32,B,13) x2 where slices 0..30 are broadcast copies of the input.
//
// R1: h[64] un-chunked -> VGPR=256 + spill, 4.8 GB scratch fetch, 4.25 ms.
// R3: __launch_bounds__(256,4) -> allocator spilled everything, WORSE.
// R5: CHUNK=8 rolled chunk loop -> spill dead (VGPR 120, FETCH 19 MB), 160 us.
//     But VALUBusy only 40%: ~784 wave-uniform broadcast ds_reads/step/wave
//     (weights) hammer the per-CU LDS port (4 waves share it) and expose
//     ds latency to the single grid-limited compute wave per SIMD.
// R6 (this): weights are wave-uniform -> move them to the SCALAR pipe.
//     v_fma_f32 takes one SGPR operand at full rate, so weights live in
//     SGPRs via s_load_dwordx16 (K$-cached), LDS removed entirely.
//     - prep kernel stages padded W2 (64x16), b1, b2p, and a 64B-aligned
//       W1 copy into d_ws so SMEM loads provably merge to dwordx16.
//     - per-step volatile pointer-launder asm ("+s", NO memory clobber:
//       a clobber would defeat the noclobber analysis that licenses
//       s_load) blocks LICM from hoisting 2700 invariant weight loads
//       into an SGPR-spill catastrophe.
//     - i-loop unroll 2 bounds in-flight SGPR load window (<102 budget).
//     Numerics bit-identical to R5 (same accumulation order, same s*k).
//
// Role-split single launch (concurrent BW + compute):
//   blocks [0, CB)      : compute — 1 thread/batch elem, weights in SGPRs.
//   blocks [CB, CB+CPB) : copy — float4 broadcast of T_room/T_wall into
//                         output slices 0..30, nontemporal stores.

#define STATE 13
#define HID   64
#define INDIM 29   // 2*STATE + 3
#define PRED  32
#define NSTEP 15

typedef float vfloat4 __attribute__((ext_vector_type(4)));

constexpr int B          = 65536;
constexpr int B13        = B * STATE;            // floats per slice
constexpr int B13_4      = B13 / 4;              // float4s per slice
constexpr int CB         = B / 256;              // 256 compute blocks
constexpr int CPB        = B13_4 / 256;          // 832 copy blocks

// Workspace layout (floats). All section bases 64B-aligned for dwordx16.
constexpr int WS_W2P    = 0;                     // (64,16) W2 padded, 4096 B
constexpr int WS_B1     = 1024;                  // 64 floats
constexpr int WS_B2P    = 1088;                  // 16 floats (padded b2)
constexpr int WS_W1     = 1152;                  // 29*64 floats, rows 256 B
constexpr int WS_FLOATS = WS_W1 + INDIM * HID;   // 3008 floats = 12032 B

__global__ __launch_bounds__(256) void ffcosta_prep(
    const float* __restrict__ W1, const float* __restrict__ b1,
    const float* __restrict__ W2, const float* __restrict__ b2,
    float* __restrict__ ws)
{
    const int tid = threadIdx.x;
    for (int idx = tid; idx < HID * 16; idx += 256) {
        const int j = idx >> 4, c = idx & 15;
        ws[WS_W2P + idx] = (c < STATE) ? W2[j * STATE + c] : 0.0f;
    }
    if (tid < HID) ws[WS_B1 + tid] = b1[tid];
    if (tid < 16)  ws[WS_B2P + tid] = (tid < STATE) ? b2[tid] : 0.0f;
    for (int idx = tid; idx < INDIM * HID; idx += 256)
        ws[WS_W1 + idx] = W1[idx];
}

__global__ __launch_bounds__(256) void ffcosta_kernel(
    const float* __restrict__ T_room, const float* __restrict__ T_wall,
    const float* __restrict__ T_out,  const float* __restrict__ door,
    const float* __restrict__ timing,
    const float* __restrict__ k_rw,   const float* __restrict__ k_ro,
    const float* __restrict__ k_wr,   const float* __restrict__ k_wo,
    const float* __restrict__ ws,
    float* __restrict__ out)
{
    float* out0 = out;                 // T_room_new, (32,B,13)
    float* out1 = out + PRED * B13;    // T_wall_new, (32,B,13)

    if (blockIdx.x >= CB) {
        // ---------------- copy role ----------------
        const int ct = (blockIdx.x - CB) * 256 + threadIdx.x;  // [0, B13_4)
        const vfloat4 r = ((const vfloat4*)T_room)[ct];
        const vfloat4 w = ((const vfloat4*)T_wall)[ct];
        vfloat4* o0 = (vfloat4*)out0 + ct;
        vfloat4* o1 = (vfloat4*)out1 + ct;
        #pragma unroll 1
        for (int p = 0; p < PRED - 1; ++p) {
            __builtin_nontemporal_store(r, o0);
            __builtin_nontemporal_store(w, o1);
            o0 += B13_4;
            o1 += B13_4;
        }
        return;
    }

    // ---------------- compute role ----------------
    const float s    = 60.0f / 3600.0f;
    const float s001 = s * 0.01f;

    const int b = blockIdx.x * 256 + threadIdx.x;

    // x[] doubles as the state carrier: x[0..12]=Tr_hat, x[13..25]=Tw_hat.
    float x[INDIM];
    #pragma unroll
    for (int c = 0; c < STATE; ++c) {
        x[c]         = T_room[b * STATE + c];
        x[STATE + c] = T_wall[b * STATE + c];
    }
    const float To = T_out [b * PRED + (PRED - 1)];
    const float d  = door  [b * PRED + (PRED - 1)];
    const float t  = timing[b * PRED + (PRED - 1)];
    x[2 * STATE]     = To;
    x[2 * STATE + 1] = d;
    x[2 * STATE + 2] = t;

    // s*k constants in VGPRs (52 regs), computed once. Uniform scalar loads.
    float sk0[STATE], sk1[STATE], sk2[STATE], sk3[STATE];
    #pragma unroll
    for (int c = 0; c < STATE; ++c) {
        sk0[c] = s * k_rw[c];
        sk1[c] = s * k_ro[c];
        sk2[c] = s * k_wr[c];
        sk3[c] = s * k_wo[c];
    }

    #pragma unroll 1   // keep the step loop rolled
    for (int n = 0; n < NSTEP; ++n) {
        // Launder the weight base pointer each step so LICM cannot hoist
        // the (loop-invariant) weight loads out of the recurrence. NO
        // memory clobber: that would defeat scalar-load (noclobber)
        // analysis. Then re-assert alignment for dwordx16 merging.
        const float* wp0 = ws;
        asm volatile("" : "+s"(wp0));
        const float* wp = (const float*)__builtin_assume_aligned(wp0, 256);

        // pbm with src=0, in place: Tr,Tw (in x) -> Tr_hat,Tw_hat (in x).
        // Note Tw_next == Tw_hat exactly; Tr_next == Tr_hat + s*0.01*src_raw.
        #pragma unroll
        for (int c = 0; c < STATE; ++c) {
            const float Trc = x[c], Twc = x[STATE + c];
            const float dA = Twc - Trc;
            const float dB = To  - Trc;
            const float dC = To  - Twc;
            float trh = fmaf(dA, sk0[c], Trc);
            trh       = fmaf(dB, sk1[c], trh);
            float twh = fmaf(-dA, sk2[c], Twc);
            twh       = fmaf(dC,  sk3[c], twh);
            x[c]         = trh;
            x[STATE + c] = twh;
        }

        // h = x @ W1 + b1  — weights via scalar pipe (SGPR operand in fma).
        float h[HID];
        #pragma unroll
        for (int j = 0; j < HID; ++j) h[j] = wp[WS_B1 + j];

        #pragma unroll 2   // bound in-flight s_load window (SGPR budget 102)
        for (int i = 0; i < INDIM; ++i) {
            const float xi = x[i];
            #pragma unroll
            for (int j = 0; j < HID; ++j)
                h[j] = fmaf(xi, wp[WS_W1 + i * HID + j], h[j]);
        }

        // src_raw = relu(h) @ W2 + b2  — padded-16 rows, one dwordx16 each.
        float src[STATE];
        #pragma unroll
        for (int c = 0; c < STATE; ++c) src[c] = wp[WS_B2P + c];

        #pragma unroll 4
        for (int j = 0; j < HID; ++j) {
            const float hv = fmaxf(h[j], 0.0f);
            #pragma unroll
            for (int c = 0; c < STATE; ++c)
                src[c] = fmaf(hv, wp[WS_W2P + j * 16 + c], src[c]);
        }

        // state update: Tr = Tr_hat + s*0.01*src_raw ; Tw = Tw_hat (in place)
        #pragma unroll
        for (int c = 0; c < STATE; ++c)
            x[c] = fmaf(src[c], s001, x[c]);
    }

    // final slice p = 31
    #pragma unroll
    for (int c = 0; c < STATE; ++c) {
        out0[(PRED - 1) * B13 + b * STATE + c] = x[c];
        out1[(PRED - 1) * B13 + b * STATE + c] = x[STATE + c];
    }
}

extern "C" void kernel_launch(void* const* d_in, const int* in_sizes, int n_in,
                              void* d_out, int out_size, void* d_ws, size_t ws_size,
                              hipStream_t stream) {
    const float* T_room = (const float*)d_in[0];
    const float* T_wall = (const float*)d_in[1];
    const float* T_out  = (const float*)d_in[2];
    const float* door   = (const float*)d_in[3];
    const float* timing = (const float*)d_in[4];
    const float* k_rw   = (const float*)d_in[5];
    const float* k_ro   = (const float*)d_in[6];
    const float* k_wr   = (const float*)d_in[7];
    const float* k_wo   = (const float*)d_in[8];
    const float* W1     = (const float*)d_in[9];
    const float* b1     = (const float*)d_in[10];
    const float* W2     = (const float*)d_in[11];
    const float* b2     = (const float*)d_in[12];
    float* out = (float*)d_out;
    float* ws  = (float*)d_ws;

    ffcosta_prep<<<1, 256, 0, stream>>>(W1, b1, W2, b2, ws);
    ffcosta_kernel<<<CB + CPB, 256, 0, stream>>>(
        T_room, T_wall, T_out, door, timing,
        k_rw, k_ro, k_wr, k_wo, ws, out);
}

// Round 3
// 455.982 us; speedup vs baseline: 7.8775x; 7.8775x over previous
//
#include <hip/hip_runtime.h>

// FFCoSTA: 15-step thermal recurrence (pbm + tiny MLP) over B=65536 elements,
// output = (32,B,13) x2 where slices 0..30 are broadcast copies of the input.
//
// R1: h[64] un-chunked -> VGPR=256 + spill, 4.8 GB scratch fetch, 4.25 ms.
// R3: __launch_bounds__(256,4) -> allocator spilled everything, WORSE.
// R5: CHUNK=8 rolled chunk loop, weights in LDS -> VGPR 120, 160 us,
//     VALUBusy 40%: ds_read latency exposed to 1 wave/SIMD + LDS port share.
// R6: weights -> scalar pipe, but W2 stage used `#pragma unroll 4` over j:
//     runtime j index into h[64] -> WHOLE h array demoted to scratch
//     (rule #20). WRITE 2.33 GB (scratch evictions), VALUBusy 2%, 3.4 ms.
//     SGPR 80 suggests s_load scalarization itself fired. Theory untested.
// R7 (this): R6 retried with register discipline restored:
//     - EXACT R5 chunk structure (rolled j0, chunk-local h[CHUNK], fully
//       unrolled jj/i inner loops -> all register indices compile-time).
//     - CHUNK=16: weight loads no longer consume VGPRs, so the R4 hazard
//       (scheduler hoisting vector loads) is structurally gone.
//     - launder a ZERO INT OFFSET (not the pointer) per step: keeps `ws`
//       kernel-arg provenance (licenses s_load/noclobber), still blocks
//       LICM from hoisting 2760 invariant weight loads across steps.
//       __builtin_assume((z&15)==0) preserves 64B alignment for dwordx16.
//     - sk[] pinned to VGPRs ("+v") so 52 uniform consts don't eat the
//       ~102-SGPR budget needed for in-flight s_load windows.
//     Numerics bit-identical to R5 (same fmaf order).
//
// Role-split single launch (concurrent BW + compute):
//   blocks [0, CB)      : compute — 1 thread/batch elem, weights via SGPRs.
//   blocks [CB, CB+CPB) : copy — float4 broadcast of T_room/T_wall into
//                         output slices 0..30, nontemporal stores.

#define STATE 13
#define HID   64
#define INDIM 29   // 2*STATE + 3
#define PRED  32
#define NSTEP 15
#define CHUNK 16

typedef float vfloat4 __attribute__((ext_vector_type(4)));

constexpr int B          = 65536;
constexpr int B13        = B * STATE;            // floats per slice
constexpr int B13_4      = B13 / 4;              // float4s per slice
constexpr int CB         = B / 256;              // 256 compute blocks
constexpr int CPB        = B13_4 / 256;          // 832 copy blocks

// Workspace layout (float indices). All section bases 64B-aligned.
constexpr int WS_W2P = 0;                        // (64,16) W2 padded
constexpr int WS_B1  = 1024;                     // 64 floats
constexpr int WS_B2P = 1088;                     // 16 floats (padded b2)
constexpr int WS_W1  = 1152;                     // 29*64 floats, rows 256 B

__global__ __launch_bounds__(256) void ffcosta_prep(
    const float* __restrict__ W1, const float* __restrict__ b1,
    const float* __restrict__ W2, const float* __restrict__ b2,
    float* __restrict__ ws)
{
    const int tid = threadIdx.x;
    for (int idx = tid; idx < HID * 16; idx += 256) {
        const int j = idx >> 4, c = idx & 15;
        ws[WS_W2P + idx] = (c < STATE) ? W2[j * STATE + c] : 0.0f;
    }
    if (tid < HID) ws[WS_B1 + tid] = b1[tid];
    if (tid < 16)  ws[WS_B2P + tid] = (tid < STATE) ? b2[tid] : 0.0f;
    for (int idx = tid; idx < INDIM * HID; idx += 256)
        ws[WS_W1 + idx] = W1[idx];
}

__global__ __launch_bounds__(256) void ffcosta_kernel(
    const float* __restrict__ T_room, const float* __restrict__ T_wall,
    const float* __restrict__ T_out,  const float* __restrict__ door,
    const float* __restrict__ timing,
    const float* __restrict__ k_rw,   const float* __restrict__ k_ro,
    const float* __restrict__ k_wr,   const float* __restrict__ k_wo,
    const float* __restrict__ ws,
    float* __restrict__ out)
{
    float* out0 = out;                 // T_room_new, (32,B,13)
    float* out1 = out + PRED * B13;    // T_wall_new, (32,B,13)

    if (blockIdx.x >= CB) {
        // ---------------- copy role ----------------
        const int ct = (blockIdx.x - CB) * 256 + threadIdx.x;  // [0, B13_4)
        const vfloat4 r = ((const vfloat4*)T_room)[ct];
        const vfloat4 w = ((const vfloat4*)T_wall)[ct];
        vfloat4* o0 = (vfloat4*)out0 + ct;
        vfloat4* o1 = (vfloat4*)out1 + ct;
        #pragma unroll 1
        for (int p = 0; p < PRED - 1; ++p) {
            __builtin_nontemporal_store(r, o0);
            __builtin_nontemporal_store(w, o1);
            o0 += B13_4;
            o1 += B13_4;
        }
        return;
    }

    // ---------------- compute role ----------------
    const float* wsf = (const float*)__builtin_assume_aligned(ws, 256);

    const float s    = 60.0f / 3600.0f;
    const float s001 = s * 0.01f;

    const int b = blockIdx.x * 256 + threadIdx.x;

    // x[] doubles as the state carrier: x[0..12]=Tr_hat, x[13..25]=Tw_hat.
    float x[INDIM];
    #pragma unroll
    for (int c = 0; c < STATE; ++c) {
        x[c]         = T_room[b * STATE + c];
        x[STATE + c] = T_wall[b * STATE + c];
    }
    const float To = T_out [b * PRED + (PRED - 1)];
    const float d  = door  [b * PRED + (PRED - 1)];
    const float t  = timing[b * PRED + (PRED - 1)];
    x[2 * STATE]     = To;
    x[2 * STATE + 1] = d;
    x[2 * STATE + 2] = t;

    // s*k constants, pinned to VGPRs so they don't occupy the SGPR budget
    // needed for the in-flight s_load weight windows.
    float sk0[STATE], sk1[STATE], sk2[STATE], sk3[STATE];
    #pragma unroll
    for (int c = 0; c < STATE; ++c) {
        sk0[c] = s * k_rw[c];  asm volatile("" : "+v"(sk0[c]));
        sk1[c] = s * k_ro[c];  asm volatile("" : "+v"(sk1[c]));
        sk2[c] = s * k_wr[c];  asm volatile("" : "+v"(sk2[c]));
        sk3[c] = s * k_wo[c];  asm volatile("" : "+v"(sk3[c]));
    }

    #pragma unroll 1   // keep the step loop rolled
    for (int n = 0; n < NSTEP; ++n) {
        // Zero offset laundered through an SGPR each step: weight addresses
        // become loop-variant (LICM cannot hoist 2760 loads across steps)
        // while `ws` keeps kernel-arg provenance (s_load scalarization OK).
        int z = 0;
        asm volatile("" : "+s"(z));
        __builtin_assume((z & 15) == 0);   // 64B alignment kept for dwordx16

        // pbm with src=0, in place: Tr,Tw (in x) -> Tr_hat,Tw_hat (in x).
        #pragma unroll
        for (int c = 0; c < STATE; ++c) {
            const float Trc = x[c], Twc = x[STATE + c];
            const float dA = Twc - Trc;
            const float dB = To  - Trc;
            const float dC = To  - Twc;
            float trh = fmaf(dA, sk0[c], Trc);
            trh       = fmaf(dB, sk1[c], trh);
            float twh = fmaf(-dA, sk2[c], Twc);
            twh       = fmaf(dC,  sk3[c], twh);
            x[c]         = trh;
            x[STATE + c] = twh;
        }

        float src[STATE];
        #pragma unroll
        for (int c = 0; c < STATE; ++c) src[c] = wsf[WS_B2P + z + c];

        // ROLLED chunk loop; h[CHUNK] chunk-local, ALL indices compile-time.
        #pragma unroll 1
        for (int j0 = 0; j0 < HID; j0 += CHUNK) {
            float h[CHUNK];
            #pragma unroll
            for (int jj = 0; jj < CHUNK; ++jj)
                h[jj] = wsf[WS_B1 + z + j0 + jj];

            #pragma unroll 2   // bound in-flight s_load window
            for (int i = 0; i < INDIM; ++i) {
                const float xi = x[i];
                #pragma unroll
                for (int q = 0; q < CHUNK / 4; ++q) {
                    const vfloat4 w =
                        *(const vfloat4*)&wsf[WS_W1 + z + i * HID + j0 + 4 * q];
                    h[4 * q + 0] = fmaf(xi, w.x, h[4 * q + 0]);
                    h[4 * q + 1] = fmaf(xi, w.y, h[4 * q + 1]);
                    h[4 * q + 2] = fmaf(xi, w.z, h[4 * q + 2]);
                    h[4 * q + 3] = fmaf(xi, w.w, h[4 * q + 3]);
                }
            }

            #pragma unroll
            for (int jj = 0; jj < CHUNK; ++jj) {
                const float hv = fmaxf(h[jj], 0.0f);
                const float* w2 = &wsf[WS_W2P + z + (j0 + jj) * 16];
                #pragma unroll
                for (int q = 0; q < 3; ++q) {
                    const vfloat4 w = *(const vfloat4*)&w2[4 * q];
                    src[4 * q + 0] = fmaf(hv, w.x, src[4 * q + 0]);
                    src[4 * q + 1] = fmaf(hv, w.y, src[4 * q + 1]);
                    src[4 * q + 2] = fmaf(hv, w.z, src[4 * q + 2]);
                }
                src[12] = fmaf(hv, w2[12], src[12]);
            }
        }

        // state update: Tr = Tr_hat + s*0.01*src_raw ; Tw = Tw_hat (in place)
        #pragma unroll
        for (int c = 0; c < STATE; ++c)
            x[c] = fmaf(src[c], s001, x[c]);
    }

    // final slice p = 31
    #pragma unroll
    for (int c = 0; c < STATE; ++c) {
        out0[(PRED - 1) * B13 + b * STATE + c] = x[c];
        out1[(PRED - 1) * B13 + b * STATE + c] = x[STATE + c];
    }
}

extern "C" void kernel_launch(void* const* d_in, const int* in_sizes, int n_in,
                              void* d_out, int out_size, void* d_ws, size_t ws_size,
                              hipStream_t stream) {
    const float* T_room = (const float*)d_in[0];
    const float* T_wall = (const float*)d_in[1];
    const float* T_out  = (const float*)d_in[2];
    const float* door   = (const float*)d_in[3];
    const float* timing = (const float*)d_in[4];
    const float* k_rw   = (const float*)d_in[5];
    const float* k_ro   = (const float*)d_in[6];
    const float* k_wr   = (const float*)d_in[7];
    const float* k_wo   = (const float*)d_in[8];
    const float* W1     = (const float*)d_in[9];
    const float* b1     = (const float*)d_in[10];
    const float* W2     = (const float*)d_in[11];
    const float* b2     = (const float*)d_in[12];
    float* out = (float*)d_out;
    float* ws  = (float*)d_ws;

    ffcosta_prep<<<1, 256, 0, stream>>>(W1, b1, W2, b2, ws);
    ffcosta_kernel<<<CB + CPB, 256, 0, stream>>>(
        T_room, T_wall, T_out, door, timing,
        k_rw, k_ro, k_wr, k_wo, ws, out);
}

// Round 4
// 287.834 us; speedup vs baseline: 12.4794x; 1.5842x over previous
//
#include <hip/hip_runtime.h>

// FFCoSTA: 15-step thermal recurrence (pbm + tiny MLP) over B=65536 elements,
// output = (32,B,13) x2 where slices 0..30 are broadcast copies of the input.
//
// R1:  h[64] un-chunked -> VGPR=256 + spill, 4.8 GB scratch, 4.25 ms.
// R5:  CHUNK=8 rolled, weights in LDS -> 160 us, VALUBusy 40%. LDS-port bound:
//      ~376 broadcast ds_read_b128/step/wave x 12cy x 4 waves/CU x 15 = 113 us
//      of pure LDS delivery; 1 compute wave/SIMD -> no latency hiding.
// R6:  weights->SGPR but runtime-indexed h[64] -> scratch (rule #20), 3.4 ms.
// R7:  R6 fixed -> s_load path works (SGPR 112, 0 scratch) but 260 us,
//      VALU 17%: s_load->fma chains serialize at 1 wave/SIMD. Both R5/R7 die
//      on per-step weight DELIVERY x no TLP.
// R8 (this): MFMA with element-per-column layout; weights live in REGISTERS.
//      - swapped operands: hT = W1T@xT, srcT = W2T@hT via mfma_16x16x32_bf16.
//        W1T/W2T A-frags + b1/b2 C-frags preloaded per lane (prep kernel
//        writes fragment tables to ws). ZERO per-step weight traffic.
//      - srcT C/D layout (col=lane&15=elem, row=4*(lane>>4)+reg=state dim)
//        IS the state layout: pbm stays exact fp32 in regs; sk = f32x4/lane.
//      - bf16 quantization only on mfma input copies, with x_lo/h_lo
//        compensation mfmas (err ~1e-3 final vs 0.125 tol).
//      - per-step LDS: 12 b64 writes + 6 b128 reads (vs R5's 376), XOR-
//        swizzled per-wave-private tiles, NO barriers.
//      - 16 elems/wave -> 4096 waves -> 4 waves/SIMD TLP.
//      - copy role FOLDED into the step loop (4 nt-stores/step, no loads
//        in-loop -> no vmcnt interference); writes drain under compute.
//      Fragment k-layout k=8*(lane>>4)+elem per ref-checked m91/m92 GEMMs.

#define STATE 13
#define HID   64
#define PRED  32
#define NSTEP 15

typedef float    f32x4 __attribute__((ext_vector_type(4)));
typedef short    s16x8 __attribute__((ext_vector_type(8)));
typedef unsigned u32x2 __attribute__((ext_vector_type(2)));
typedef float    vfloat4 __attribute__((ext_vector_type(4)));

constexpr int B      = 65536;
constexpr int B13    = B * STATE;     // 851968 floats per slice
constexpr int B13_4  = B13 / 4;       // 212992 float4s per slice
constexpr int CBLK   = B / 64;        // 1024 blocks, 64 elems each

// ws byte offsets (fragment tables, 15360 B total)
constexpr int WS_W1F = 0;        // [4 tiles][64 lanes] s16x8  = 4096 B
constexpr int WS_W2F = 4096;     // [2 slices][64]      s16x8  = 2048 B
constexpr int WS_B1C = 6144;     // [4][64]             f32x4  = 4096 B
constexpr int WS_B2C = 10240;    // [64]                f32x4  = 1024 B
constexpr int WS_SK  = 11264;    // [4][64]             f32x4  = 4096 B

__device__ __forceinline__ unsigned short f2bf(float f) {
    return __builtin_bit_cast(unsigned short, (__bf16)f);
}
__device__ __forceinline__ unsigned pkbf(float lo, float hi) {
    return (unsigned)f2bf(lo) | ((unsigned)f2bf(hi) << 16);
}
__device__ __forceinline__ float bflo(unsigned u) { return __builtin_bit_cast(float, u << 16); }
__device__ __forceinline__ float bfhi(unsigned u) { return __builtin_bit_cast(float, u & 0xffff0000u); }

// x-dim layout (32): [0..12]=Tr, [13..15]=0 pad, [16..28]=Tw, [29..31]=To,d,t.
// W1 orig rows: 0-12 Tr, 13-25 Tw, 26-28 extras -> orig = nd<13 ? nd : nd-3.
__global__ __launch_bounds__(256) void ffcosta_prep(
    const float* __restrict__ W1, const float* __restrict__ b1,
    const float* __restrict__ W2, const float* __restrict__ b2,
    const float* __restrict__ k_rw, const float* __restrict__ k_ro,
    const float* __restrict__ k_wr, const float* __restrict__ k_wo,
    char* __restrict__ ws)
{
    const int tid = threadIdx.x;
    const float s = 60.0f / 3600.0f;

    // W1T A-frags: A[m=j][k=nd], lane: m=16t+(l&15), k=8*(l>>4)+r
    unsigned short* w1f = (unsigned short*)(ws + WS_W1F);
    for (int idx = tid; idx < 4*64*8; idx += 256) {
        const int t = idx >> 9, l = (idx >> 3) & 63, r = idx & 7;
        const int nd = 8*(l>>4) + r;
        const int j  = 16*t + (l & 15);
        float v = 0.0f;
        if (nd < 13)       v = W1[nd*HID + j];
        else if (nd >= 16) v = W1[(nd-3)*HID + j];
        w1f[idx] = f2bf(v);
    }
    // W2T A-frags: A[m=c][k=j], lane: c=l&15, j=32s+8*(l>>4)+r
    unsigned short* w2f = (unsigned short*)(ws + WS_W2F);
    for (int idx = tid; idx < 2*64*8; idx += 256) {
        const int sl = idx >> 9, l = (idx >> 3) & 63, r = idx & 7;
        const int j = 32*sl + 8*(l>>4) + r;
        const int c = l & 15;
        w2f[idx] = (c < STATE) ? f2bf(W2[j*STATE + c]) : (unsigned short)0;
    }
    // b1 C-frags: C row = m = 16t + 4*(l>>4) + r
    float* b1c = (float*)(ws + WS_B1C);
    for (int idx = tid; idx < 4*64*4; idx += 256) {
        const int t = idx >> 8, l = (idx >> 2) & 63, r = idx & 3;
        b1c[idx] = b1[16*t + 4*(l>>4) + r];
    }
    // b2 C-frag: row = c = 4*(l>>4) + r, pad rows 13-15 = 0
    float* b2c = (float*)(ws + WS_B2C);
    for (int idx = tid; idx < 64*4; idx += 256) {
        const int l = idx >> 2, r = idx & 3;
        const int c = 4*(l>>4) + r;
        b2c[idx] = (c < STATE) ? b2[c] : 0.0f;
    }
    // s*k per lane (state dim = 4*(l>>4)+r), pad dims -> 0 (pbm no-op on pads)
    float* sk = (float*)(ws + WS_SK);
    for (int idx = tid; idx < 4*64*4; idx += 256) {
        const int a = idx >> 8, l = (idx >> 2) & 63, r = idx & 3;
        const int c = 4*(l>>4) + r;
        const float* ka = (a==0)? k_rw : (a==1)? k_ro : (a==2)? k_wr : k_wo;
        sk[idx] = (c < STATE) ? s * ka[c] : 0.0f;
    }
}

__global__ __launch_bounds__(256) void ffcosta_kernel(
    const float* __restrict__ T_room, const float* __restrict__ T_wall,
    const float* __restrict__ T_out,  const float* __restrict__ door,
    const float* __restrict__ timing,
    const char*  __restrict__ ws,
    float* __restrict__ out)
{
    // per-wave-private LDS tiles (no barriers anywhere):
    // +0:    x_hi  16 rows x 64 B   (bf16, x-dim byte = 2*nd)
    // +1024: x_lo
    // +2048: h_hi  16 rows x 128 B  (bf16, byte = 2*j)
    // +4096: h_lo      -> 6144 B per wave, 24576 per block
    __shared__ __align__(16) char smem[4 * 6144];

    const int tid  = threadIdx.x;
    const int lane = tid & 63, w = tid >> 6;
    const int el   = lane & 15, hi = lane >> 4;
    const int e    = blockIdx.x * 64 + w * 16 + el;

    // ---- invariant per-lane preloads (weights live in VGPRs) ----
    s16x8 w1a[4], w2a[2];
    f32x4 b1c[4], b2c, skrw, skro, skwr, skwo;
    #pragma unroll
    for (int t = 0; t < 4; ++t) {
        w1a[t] = *(const s16x8*)(ws + WS_W1F + (t*64 + lane)*16);
        b1c[t] = *(const f32x4*)(ws + WS_B1C + (t*64 + lane)*16);
    }
    #pragma unroll
    for (int sl = 0; sl < 2; ++sl)
        w2a[sl] = *(const s16x8*)(ws + WS_W2F + (sl*64 + lane)*16);
    b2c  = *(const f32x4*)(ws + WS_B2C + lane*16);
    skrw = *(const f32x4*)(ws + WS_SK +        lane*16);
    skro = *(const f32x4*)(ws + WS_SK + 1024 + lane*16);
    skwr = *(const f32x4*)(ws + WS_SK + 2048 + lane*16);
    skwo = *(const f32x4*)(ws + WS_SK + 3072 + lane*16);

    // ---- state init: lane holds state dims 4*hi + r for element e ----
    // hi==3 lanes: Tr[0]=Tr[12], Tw[0]=Tw[12], Tw[1..3]=To,d,t (x dims 29-31);
    // their sk pads are 0 so pbm passes them through untouched.
    const int off4 = (hi < 3) ? 4*hi : 9;   // hi=3 loads dims 9..12, uses .w
    f32x4 vr, vw;
    __builtin_memcpy(&vr, T_room + e*STATE + off4, 16);
    __builtin_memcpy(&vw, T_wall + e*STATE + off4, 16);
    const float To = T_out [e*PRED + (PRED-1)];
    const float dv = door  [e*PRED + (PRED-1)];
    const float tv = timing[e*PRED + (PRED-1)];
    float Tr[4], Tw[4];
    if (hi < 3) {
        Tr[0]=vr[0]; Tr[1]=vr[1]; Tr[2]=vr[2]; Tr[3]=vr[3];
        Tw[0]=vw[0]; Tw[1]=vw[1]; Tw[2]=vw[2]; Tw[3]=vw[3];
    } else {
        Tr[0]=vr[3]; Tr[1]=0.0f; Tr[2]=0.0f; Tr[3]=0.0f;
        Tw[0]=vw[3]; Tw[1]=To;   Tw[2]=dv;   Tw[3]=tv;
    }

    // ---- broadcast-copy role (folded): 1 float4 per thread per slice ----
    const int  cf = blockIdx.x * 256 + tid;
    const bool cvalid = cf < B13_4;
    vfloat4 crm = {0,0,0,0}, cwl = {0,0,0,0};
    if (cvalid) {
        crm = ((const vfloat4*)T_room)[cf];
        cwl = ((const vfloat4*)T_wall)[cf];
    }
    vfloat4* out0_4 = (vfloat4*)out;
    vfloat4* out1_4 = (vfloat4*)(out + (size_t)PRED * B13);

    // ---- LDS offsets (XOR-swizzled, step-invariant) ----
    const int wb = w * 6144;
    const int xk = (el & 3) << 4;          // x-tile row = 64 B
    const int hk = (el & 7) << 4;          // h-tile row = 128 B
    const int a_xw_tr = wb + el*64 + (( 8*hi) ^ xk);   // Tr dims -> bytes 8hi+2r
    const int a_xw_tw = wb + el*64 + ((32 + 8*hi) ^ xk);
    const int a_xr    = wb + el*64 + ((16*hi) ^ xk);   // k = 8hi..8hi+7
    int a_hw[4], a_hr[2];
    #pragma unroll
    for (int t = 0; t < 4; ++t) a_hw[t] = wb + 2048 + el*128 + ((32*t + 8*hi) ^ hk);
    #pragma unroll
    for (int sl = 0; sl < 2; ++sl) a_hr[sl] = wb + 2048 + el*128 + ((64*sl + 16*hi) ^ hk);

    const float s001 = (60.0f/3600.0f) * 0.01f;

    #pragma unroll 1
    for (int n = 0; n < NSTEP; ++n) {
        // copy stores for slices 2n, 2n+1 (fire-and-forget, drains under compute)
        if (cvalid) {
            const int i0 = (2*n) * B13_4 + cf;
            __builtin_nontemporal_store(crm, out0_4 + i0);
            __builtin_nontemporal_store(crm, out0_4 + i0 + B13_4);
            __builtin_nontemporal_store(cwl, out1_4 + i0);
            __builtin_nontemporal_store(cwl, out1_4 + i0 + B13_4);
        }

        // pbm, exact fp32 in registers (pad rows: sk=0 -> identity)
        #pragma unroll
        for (int r = 0; r < 4; ++r) {
            const float dA = Tw[r] - Tr[r];
            const float dB = To    - Tr[r];
            const float dC = To    - Tw[r];
            Tr[r] = fmaf(dB, skro[r], fmaf(dA, skrw[r], Tr[r]));
            Tw[r] = fmaf(dC, skwo[r], fmaf(-dA, skwr[r], Tw[r]));
        }

        // pack x_hi + residual x_lo, write (2+2 b64)
        const unsigned tr01 = pkbf(Tr[0], Tr[1]), tr23 = pkbf(Tr[2], Tr[3]);
        const unsigned tw01 = pkbf(Tw[0], Tw[1]), tw23 = pkbf(Tw[2], Tw[3]);
        u32x2 v;
        v[0]=tr01; v[1]=tr23; *(u32x2*)(smem + a_xw_tr) = v;
        v[0]=tw01; v[1]=tw23; *(u32x2*)(smem + a_xw_tw) = v;
        v[0]=pkbf(Tr[0]-bflo(tr01), Tr[1]-bfhi(tr01));
        v[1]=pkbf(Tr[2]-bflo(tr23), Tr[3]-bfhi(tr23));
        *(u32x2*)(smem + a_xw_tr + 1024) = v;
        v[0]=pkbf(Tw[0]-bflo(tw01), Tw[1]-bfhi(tw01));
        v[1]=pkbf(Tw[2]-bflo(tw23), Tw[3]-bfhi(tw23));
        *(u32x2*)(smem + a_xw_tw + 1024) = v;

        // B-frags for layer 1 (same-wave lgkmcnt ordering, no barrier)
        const s16x8 xbh = *(const s16x8*)(smem + a_xr);
        const s16x8 xbl = *(const s16x8*)(smem + a_xr + 1024);

        // layer 1: hT[j][e] = b1 + W1T@x_hi + W1T@x_lo
        f32x4 acc[4];
        #pragma unroll
        for (int t = 0; t < 4; ++t) {
            acc[t] = __builtin_amdgcn_mfma_f32_16x16x32_bf16(w1a[t], xbh, b1c[t], 0, 0, 0);
            acc[t] = __builtin_amdgcn_mfma_f32_16x16x32_bf16(w1a[t], xbl, acc[t], 0, 0, 0);
        }

        // relu, pack h_hi + h_lo, write (4+4 b64)
        #pragma unroll
        for (int t = 0; t < 4; ++t) {
            const float h0 = fmaxf(acc[t][0], 0.0f), h1 = fmaxf(acc[t][1], 0.0f);
            const float h2 = fmaxf(acc[t][2], 0.0f), h3 = fmaxf(acc[t][3], 0.0f);
            const unsigned p01 = pkbf(h0, h1), p23 = pkbf(h2, h3);
            u32x2 hv; hv[0]=p01; hv[1]=p23;
            *(u32x2*)(smem + a_hw[t]) = hv;
            hv[0] = pkbf(h0-bflo(p01), h1-bfhi(p01));
            hv[1] = pkbf(h2-bflo(p23), h3-bfhi(p23));
            *(u32x2*)(smem + a_hw[t] + 2048) = hv;
        }

        const s16x8 hb0 = *(const s16x8*)(smem + a_hr[0]);
        const s16x8 hb1 = *(const s16x8*)(smem + a_hr[1]);
        const s16x8 hl0 = *(const s16x8*)(smem + a_hr[0] + 2048);
        const s16x8 hl1 = *(const s16x8*)(smem + a_hr[1] + 2048);

        // layer 2: srcT[c][e] = b2 + W2T@h_hi + W2T@h_lo  (pad rows -> 0)
        f32x4 sv = b2c;
        sv = __builtin_amdgcn_mfma_f32_16x16x32_bf16(w2a[0], hb0, sv, 0, 0, 0);
        sv = __builtin_amdgcn_mfma_f32_16x16x32_bf16(w2a[1], hb1, sv, 0, 0, 0);
        sv = __builtin_amdgcn_mfma_f32_16x16x32_bf16(w2a[0], hl0, sv, 0, 0, 0);
        sv = __builtin_amdgcn_mfma_f32_16x16x32_bf16(w2a[1], hl1, sv, 0, 0, 0);

        // state update: Tr += s*0.01*src_raw (pad rows get +0)
        #pragma unroll
        for (int r = 0; r < 4; ++r) Tr[r] = fmaf(sv[r], s001, Tr[r]);
    }

    // copy slice 30
    if (cvalid) {
        const int i0 = 30 * B13_4 + cf;
        __builtin_nontemporal_store(crm, out0_4 + i0);
        __builtin_nontemporal_store(cwl, out1_4 + i0);
    }

    // final slice 31: lane stores dims 4hi..4hi+3 (hi=3: dim 12 only)
    float* p0 = out + (size_t)(PRED-1) * B13 + e*STATE;
    float* p1 = p0 + (size_t)PRED * B13;
    if (hi < 3) {
        f32x4 s0, s1;
        s0[0]=Tr[0]; s0[1]=Tr[1]; s0[2]=Tr[2]; s0[3]=Tr[3];
        s1[0]=Tw[0]; s1[1]=Tw[1]; s1[2]=Tw[2]; s1[3]=Tw[3];
        __builtin_memcpy(p0 + 4*hi, &s0, 16);
        __builtin_memcpy(p1 + 4*hi, &s1, 16);
    } else {
        p0[12] = Tr[0];
        p1[12] = Tw[0];
    }
}

extern "C" void kernel_launch(void* const* d_in, const int* in_sizes, int n_in,
                              void* d_out, int out_size, void* d_ws, size_t ws_size,
                              hipStream_t stream) {
    const float* T_room = (const float*)d_in[0];
    const float* T_wall = (const float*)d_in[1];
    const float* T_out  = (const float*)d_in[2];
    const float* door   = (const float*)d_in[3];
    const float* timing = (const float*)d_in[4];
    const float* k_rw   = (const float*)d_in[5];
    const float* k_ro   = (const float*)d_in[6];
    const float* k_wr   = (const float*)d_in[7];
    const float* k_wo   = (const float*)d_in[8];
    const float* W1     = (const float*)d_in[9];
    const float* b1     = (const float*)d_in[10];
    const float* W2     = (const float*)d_in[11];
    const float* b2     = (const float*)d_in[12];
    float* out = (float*)d_out;
    char*  ws  = (char*)d_ws;

    ffcosta_prep<<<1, 256, 0, stream>>>(W1, b1, W2, b2, k_rw, k_ro, k_wr, k_wo, ws);
    ffcosta_kernel<<<CBLK, 256, 0, stream>>>(
        T_room, T_wall, T_out, door, timing, ws, out);
}